// Round 10
// baseline (188.498 us; speedup 1.0000x reference)
//
#include <hip/hip_runtime.h>
#include <math.h>

#define C_DIMK 2048

typedef float f32x4 __attribute__((ext_vector_type(4)));

// Fully-resident streamer, spill-free. 1024 blocks (4/CU, all resident in one
// generation). Block b owns rows r0=2b, r0+1; wave w = gate w (f,i,c,o).
// Each row is streamed as two 8-load halves (8 KB) through a 2-deep ping-pong
// (bufA/bufB = 64 VGPRs total — cannot spill at 128-VGPR budget). Steady state:
// 8 KB in flight per wave x 16 waves/CU = 128 KB/CU continuously, no drains.
// sched_barrier(0) fences keep issue batches intact.

#define ISSUE8(buf, roff, hh)                                           \
  _Pragma("unroll")                                                     \
  for (int j = 0; j < 8; ++j)                                           \
    buf[j] = __builtin_nontemporal_load(                                \
        &Wm[(size_t)(roff) * 1024 + (hh) * 512 + j * 64 + lane]);

#define DOT8(buf, hh, acc)                                              \
  {                                                                     \
    float d0 = 0.f, d1 = 0.f, d2 = 0.f, d3 = 0.f;                       \
    _Pragma("unroll")                                                   \
    for (int j = 0; j < 8; ++j) {                                       \
      const f32x4 xvj = xs[(hh) * 512 + j * 64 + lane];                 \
      const f32x4 wv = buf[j];                                          \
      float d = wv.x * xvj.x;                                           \
      d = fmaf(wv.y, xvj.y, d);                                         \
      d = fmaf(wv.z, xvj.z, d);                                         \
      d = fmaf(wv.w, xvj.w, d);                                         \
      if ((j & 3) == 0) d0 += d;                                        \
      else if ((j & 3) == 1) d1 += d;                                   \
      else if ((j & 3) == 2) d2 += d;                                   \
      else d3 += d;                                                     \
    }                                                                   \
    acc += (d0 + d1) + (d2 + d3);                                       \
  }

__global__ __launch_bounds__(256, 4) void lstm_fused_kernel(
    const float* __restrict__ h, const float* __restrict__ c,
    const float* __restrict__ x,
    const float* __restrict__ wf, const float* __restrict__ bf,
    const float* __restrict__ wi, const float* __restrict__ bi,
    const float* __restrict__ wo, const float* __restrict__ bo,
    const float* __restrict__ wc, const float* __restrict__ bc,
    float* __restrict__ out)
{
    __shared__ f32x4 xs[1024];          // 16 KB: cat(x, h)
    __shared__ float partial[4][2];     // [wave][row]

    const int t    = threadIdx.x;
    const int wave = t >> 6;            // 0..3 -> gate f,i,c,o
    const int lane = t & 63;
    const int r0   = blockIdx.x * 2;

    // Stage cat(x,h) to LDS first; this barrier's drain covers only 4 loads.
    const f32x4* X4 = reinterpret_cast<const f32x4*>(x);
    const f32x4* H4 = reinterpret_cast<const f32x4*>(h);
    #pragma unroll
    for (int k = 0; k < 4; ++k) {
        const int idx = k * 256 + t;    // k<2 -> x, k>=2 -> h (uniform per k)
        xs[idx] = (idx < 512) ? X4[idx] : H4[idx - 512];
    }
    __syncthreads();

    // Gate order matches reference g-layout: [f, i, c, o]
    const float* W = (wave == 0) ? wf : (wave == 1) ? wi : (wave == 2) ? wc : wo;
    const f32x4* Wm = reinterpret_cast<const f32x4*>(W);

    f32x4 bufA[8], bufB[8];
    float s0 = 0.f, s1 = 0.f;

    ISSUE8(bufA, r0, 0);                // row0 half0
    __builtin_amdgcn_sched_barrier(0);
    ISSUE8(bufB, r0, 1);                // row0 half1
    __builtin_amdgcn_sched_barrier(0);
    DOT8(bufA, 0, s0);                  // waits A only; B stays in flight
    __builtin_amdgcn_sched_barrier(0);
    ISSUE8(bufA, r0 + 1, 0);            // row1 half0
    __builtin_amdgcn_sched_barrier(0);
    DOT8(bufB, 1, s0);
    __builtin_amdgcn_sched_barrier(0);
    ISSUE8(bufB, r0 + 1, 1);            // row1 half1
    __builtin_amdgcn_sched_barrier(0);
    DOT8(bufA, 0, s1);
    __builtin_amdgcn_sched_barrier(0);
    DOT8(bufB, 1, s1);

    // Wave64 reductions.
    #pragma unroll
    for (int off = 32; off > 0; off >>= 1) {
        s0 += __shfl_down(s0, off, 64);
        s1 += __shfl_down(s1, off, 64);
    }

    if (lane == 0) {
        partial[wave][0] = s0;
        partial[wave][1] = s1;
    }
    __syncthreads();

    if (t < 2) {
        const int r = r0 + t;
        const float gf = partial[0][t] + bf[r];
        const float gi = partial[1][t] + bi[r];
        const float gc = partial[2][t] + bc[r];
        const float go = partial[3][t] + bo[r];
        const float ff = 1.0f / (1.0f + __expf(-gf));
        const float ig = 1.0f / (1.0f + __expf(-gi));
        const float cc = tanhf(gc);
        const float oo = 1.0f / (1.0f + __expf(-go));
        const float cn = fmaf(ff, c[r], ig * cc);
        const float hn = tanhf(cn) * oo;
        out[r]          = cn;   // c_new
        out[C_DIMK + r] = hn;   // h_new
    }
}

extern "C" void kernel_launch(void* const* d_in, const int* in_sizes, int n_in,
                              void* d_out, int out_size, void* d_ws, size_t ws_size,
                              hipStream_t stream) {
    // setup_inputs() order: h, c, x, wf, bf, wi, bi, wo, bo, wc, bc (all fp32)
    const float* h  = (const float*)d_in[0];
    const float* c  = (const float*)d_in[1];
    const float* x  = (const float*)d_in[2];
    const float* wf = (const float*)d_in[3];
    const float* bf = (const float*)d_in[4];
    const float* wi = (const float*)d_in[5];
    const float* bi = (const float*)d_in[6];
    const float* wo = (const float*)d_in[7];
    const float* bo = (const float*)d_in[8];
    const float* wc = (const float*)d_in[9];
    const float* bc = (const float*)d_in[10];
    float* out = (float*)d_out;

    lstm_fused_kernel<<<1024, 256, 0, stream>>>(
        h, c, x, wf, bf, wi, bi, wo, bo, wc, bc, out);
}